// Round 16
// baseline (314.796 us; speedup 1.0000x reference)
//
#include <hip/hip_runtime.h>
#include <hip/hip_bf16.h>

// clusterLayer: q = rownorm( 1 / (1 + ||x||^2 + ||c||^2 - 2 x.cT) )
// N=524288, K=256, D=256. fp32 in/out.
// r16 = r13 (best, 244us) + full-d-via-MFMA aug + s_setprio on MFMA pair.
//   - Clusters in ws: -2*bf16(c), 17 frags/nj; aug frag (A-side) =
//     [limbs3(1+|c|^2), 1,1,1, 0,0] per cluster lane.
//   - Context aug frag (B-side, built post-K-loop) =
//     [1,1,1, limbs3(|x|^2), 0,0] per ctx-row lane -> aug MFMA yields
//     acc = 1 + d exactly; pass 1 is rcp-only.
//   - Swapped MFMA: C lane = ctx row, reg = cluster col. In-lane row sums,
//     dwordx4 stores straight from acc.
//   - BM=64, 512 thr = 8 waves = 8 col-eighths x 2 row-halves;
//     2 barriers; LDS ~38 KiB; launch_bounds(512,6): 3 blocks/CU.

#define DD 256
#define KC 256
#define BM 64

typedef __attribute__((ext_vector_type(4)))  float f32x4;
typedef __attribute__((ext_vector_type(16))) float f32x16;
typedef __attribute__((ext_vector_type(8)))  short bf16x8;
typedef __attribute__((ext_vector_type(4)))  short bf16x4;
typedef __attribute__((ext_vector_type(4)))  unsigned u32x4;

__device__ __forceinline__ short f2bf(float f) {
    union { float f; unsigned u; } v; v.f = f;
    unsigned r = (v.u + 0x7fffu + ((v.u >> 16) & 1u)) >> 16;
    return (short)r;
}

__device__ __forceinline__ float bf2f(short h) {
    return __builtin_bit_cast(float, ((unsigned)(unsigned short)h) << 16);
}

__device__ __forceinline__ unsigned cvtpk(float a, float b) {
    unsigned r;
    asm("v_cvt_pk_bf16_f32 %0, %1, %2" : "=v"(r) : "v"(a), "v"(b));
    return r;
}

__device__ __forceinline__ float frcp(float x) {
    return __builtin_amdgcn_rcpf(x);
}

template<int CTRL>
__device__ __forceinline__ float dpp_add(float v) {
    int iv = __builtin_bit_cast(int, v);
    int mv = __builtin_amdgcn_update_dpp(0, iv, CTRL, 0xf, 0xf, false);
    return v + __builtin_bit_cast(float, mv);
}
#define QUAD_SWAP1 0xB1    // quad_perm [1,0,3,2]

__device__ __forceinline__ f32x4 ld4(const float* p) { return *(const f32x4*)p; }

// ---------------- Kernel 0: prep clusters ----------------
// Main frags (nj*17+ks): -2*bf16(c) in 32x32x16 A-operand order.
// Aug frag (nj*17+16), k=256..263 side: [c2h,c2m,c2l, 1,1,1, 0,0] with
// (c2*) = limbs3(1+|c|^2); k=264..271 side zeros.
__global__ __launch_bounds__(64)
void prep_clusters(const float* __restrict__ clus, short* __restrict__ wsb) {
    const int c = blockIdx.x;      // cluster row 0..255
    const int t = threadIdx.x;     // 0..63, 4 floats each
    f32x4 v = *(const f32x4*)(clus + c * DD + t * 4);
    bf16x4 o;
    o[0] = f2bf(-2.f * v[0]); o[1] = f2bf(-2.f * v[1]);
    o[2] = f2bf(-2.f * v[2]); o[3] = f2bf(-2.f * v[3]);

    const int j    = t >> 1;       // 8-elem chunk index within row (k/8)
    const int ks   = j >> 1;
    const int hi   = j & 1;
    const int half = t & 1;
    const int nj   = c >> 5;
    const int l31  = c & 31;
    *(bf16x4*)&wsb[(((nj * 17 + ks) * 64 + hi * 32 + l31) << 3) + half * 4] = o;

    float s = v[0]*v[0] + v[1]*v[1] + v[2]*v[2] + v[3]*v[3];   // raw |c|^2
    s += __shfl_xor(s, 1);  s += __shfl_xor(s, 2);  s += __shfl_xor(s, 4);
    s += __shfl_xor(s, 8);  s += __shfl_xor(s, 16); s += __shfl_xor(s, 32);
    if (t == 0) {
        float e = 1.f + s;
        short h = f2bf(e);  float e1 = e - bf2f(h);
        short m = f2bf(e1); float e2 = e1 - bf2f(m);
        short l = f2bf(e2);
        const unsigned one = 0x3F80u;
        u32x4 a;
        a[0] = (unsigned)(unsigned short)h | ((unsigned)(unsigned short)m << 16);
        a[1] = (unsigned)(unsigned short)l | (one << 16);
        a[2] = one | (one << 16);
        a[3] = 0u;
        *(u32x4*)&wsb[((nj * 17 + 16) * 64 + l31) * 8] = a;         // k 256..263
        u32x4 z = {0u, 0u, 0u, 0u};
        *(u32x4*)&wsb[((nj * 17 + 16) * 64 + 32 + l31) * 8] = z;    // k 264..271
    }
}

// ---------------- Main kernel ----------------
__global__ __launch_bounds__(512, 6)
void cluster_q_main(const float* __restrict__ ctx,
                    const short* __restrict__ wsb,
                    float* __restrict__ out) {
    __shared__ short Af[32 * 64 * 8];       // 32 KiB: [j=k/8][row 0..63][8]
    __shared__ float x2p8[8][64];           // per-(wave,row) |x|^2 partials
    __shared__ float rowsum2[8][2][64];     // per-(wave,hi,row) q half-sums

    const int t    = threadIdx.x;
    const int lane = t & 63;
    const int w    = t >> 6;             // wave = col-eighth 0..7
    const int l31  = lane & 31;
    const int hi   = lane >> 5;
    const size_t row0 = (size_t)blockIdx.x * BM;

    // ---- stage A: wave w converts k-slice [w*32, w*32+32) of all 64 rows ----
    {
        const int r0   = lane >> 1;      // row 0..31 (and +32)
        const int half = lane & 1;       // 16-float half of the slice
        f32x4 u[8];
#pragma unroll
        for (int m = 0; m < 2; ++m) {
            const float* src = ctx + (row0 + (size_t)(m * 32 + r0)) * DD
                             + w * 32 + half * 16;
#pragma unroll
            for (int i = 0; i < 4; ++i)
                u[m * 4 + i] = ld4(src + i * 4);
        }
#pragma unroll
        for (int m = 0; m < 2; ++m) {
            float xs = 0.f;
#pragma unroll
            for (int c = 0; c < 2; ++c) {
                f32x4 a0 = u[m * 4 + 2 * c], a1 = u[m * 4 + 2 * c + 1];
                u32x4 o;
                o[0] = cvtpk(a0[0], a0[1]);
                o[1] = cvtpk(a0[2], a0[3]);
                o[2] = cvtpk(a1[0], a1[1]);
                o[3] = cvtpk(a1[2], a1[3]);
                xs += a0[0]*a0[0] + a0[1]*a0[1] + a0[2]*a0[2] + a0[3]*a0[3]
                    + a1[0]*a1[0] + a1[1]*a1[1] + a1[2]*a1[2] + a1[3]*a1[3];
                const int j = w * 4 + half * 2 + c;      // k/8 chunk index
                *(u32x4*)&Af[(j * 64 + m * 32 + r0) * 8] = o;
            }
            xs = dpp_add<QUAD_SWAP1>(xs);                // combine halves
            if (half == 0) x2p8[w][m * 32 + r0] = xs;
        }
    }

    // cluster fragment base: this wave's col-tile nj = w (17 frags)
    const short* bl = wsb + (size_t)(w * 17) * 512 + lane * 8;

    __syncthreads();   // B1: Af + x2p8 ready

    // per-lane |x|^2 totals (lane = ctx row l31 / 32+l31)
    float x2A = 0.f, x2B = 0.f;
#pragma unroll
    for (int q = 0; q < 8; ++q) {
        x2A += x2p8[q][l31];
        x2B += x2p8[q][32 + l31];
    }

    f32x16 acc0 = (f32x16)0.f, acc1 = (f32x16)0.f;

    // clusters: 3-slot rotation, distance 2 (L2 latency cover)
    bf16x8 bs[3];
    bs[0] = *(const bf16x8*)(bl + 0 * 512);
    bs[1] = *(const bf16x8*)(bl + 1 * 512);

    // context frags: ping-pong from LDS
    bf16x8 afA0 = *(const bf16x8*)&Af[((0 + hi) * 64 +  0 + l31) * 8];
    bf16x8 afA1 = *(const bf16x8*)&Af[((0 + hi) * 64 + 32 + l31) * 8];
    bf16x8 afB0, afB1;

#pragma unroll
    for (int ks = 0; ks < 16; ++ks) {
        const int cur = ks % 3;
        const bool even = (ks & 1) == 0;

        if (ks < 14)
            bs[(ks + 2) % 3] = *(const bf16x8*)(bl + (ks + 2) * 512);
        if (ks < 15) {
            const int jn = (ks + 1) * 2 + hi;
            bf16x8 v0 = *(const bf16x8*)&Af[(jn * 64 +  0 + l31) * 8];
            bf16x8 v1 = *(const bf16x8*)&Af[(jn * 64 + 32 + l31) * 8];
            if (even) { afB0 = v0; afB1 = v1; }
            else      { afA0 = v0; afA1 = v1; }
        }

        const bf16x8 a0 = even ? afA0 : afB0;
        const bf16x8 a1 = even ? afA1 : afB1;
        __builtin_amdgcn_s_setprio(1);
        acc0 = __builtin_amdgcn_mfma_f32_32x32x16_bf16(bs[cur], a0, acc0, 0, 0, 0);
        acc1 = __builtin_amdgcn_mfma_f32_32x32x16_bf16(bs[cur], a1, acc1, 0, 0, 0);
        __builtin_amdgcn_s_setprio(0);
    }

    // ---- aug step: acc += (1+|c|^2)*1 + 1*|x|^2  ->  acc = 1 + d ----
    {
        bf16x8 bsa = *(const bf16x8*)(bl + 16 * 512);
        const short one = (hi == 0) ? (short)0x3F80 : (short)0;

        short hA = f2bf(x2A); float rA = x2A - bf2f(hA);
        short mA = f2bf(rA);  float sA = rA - bf2f(mA);
        short lA = f2bf(sA);
        bf16x8 augA = (bf16x8)0;
        augA[0] = one; augA[1] = one; augA[2] = one;
        augA[3] = (hi == 0) ? hA : (short)0;
        augA[4] = (hi == 0) ? mA : (short)0;
        augA[5] = (hi == 0) ? lA : (short)0;

        short hB = f2bf(x2B); float rB = x2B - bf2f(hB);
        short mB = f2bf(rB);  float sB = rB - bf2f(mB);
        short lB = f2bf(sB);
        bf16x8 augB = (bf16x8)0;
        augB[0] = one; augB[1] = one; augB[2] = one;
        augB[3] = (hi == 0) ? hB : (short)0;
        augB[4] = (hi == 0) ? mB : (short)0;
        augB[5] = (hi == 0) ? lB : (short)0;

        acc0 = __builtin_amdgcn_mfma_f32_32x32x16_bf16(bsa, augA, acc0, 0, 0, 0);
        acc1 = __builtin_amdgcn_mfma_f32_32x32x16_bf16(bsa, augB, acc1, 0, 0, 0);
    }

    // ---- pass 1: q = rcp(acc), in-lane half-row sums ----
    float s0 = 0.f, s1 = 0.f;
#pragma unroll
    for (int r = 0; r < 16; ++r) {
        acc0[r] = frcp(acc0[r]); s0 += acc0[r];
        acc1[r] = frcp(acc1[r]); s1 += acc1[r];
    }
    rowsum2[w][hi][l31]      = s0;
    rowsum2[w][hi][32 + l31] = s1;
    __syncthreads();   // B2

    // ---- pass 2: row totals, normalize, dwordx4 stores ----
    float t0 = 0.f, t1 = 0.f;
#pragma unroll
    for (int q = 0; q < 8; ++q) {
        t0 += rowsum2[q][0][l31]      + rowsum2[q][1][l31];
        t1 += rowsum2[q][0][32 + l31] + rowsum2[q][1][32 + l31];
    }
    const float inv0 = frcp(t0);
    const float inv1 = frcp(t1);

    float* op0 = out + (row0 + (size_t)l31) * KC        + w * 32 + 4 * hi;
    float* op1 = out + (row0 + (size_t)(32 + l31)) * KC + w * 32 + 4 * hi;
#pragma unroll
    for (int i = 0; i < 4; ++i) {
        f32x4 v0, v1;
#pragma unroll
        for (int j = 0; j < 4; ++j) {
            v0[j] = acc0[4 * i + j] * inv0;   // cluster col = 8i + 4hi + j
            v1[j] = acc1[4 * i + j] * inv1;
        }
        *(f32x4*)(op0 + 8 * i) = v0;
        *(f32x4*)(op1 + 8 * i) = v1;
    }
}

extern "C" void kernel_launch(void* const* d_in, const int* in_sizes, int n_in,
                              void* d_out, int out_size, void* d_ws, size_t ws_size,
                              hipStream_t stream) {
    const float* ctx  = (const float*)d_in[0];
    const float* clus = (const float*)d_in[1];
    float* out = (float*)d_out;

    short* wsb = (short*)d_ws;     // cluster fragment image (8*17 KiB = 136 KiB)

    const int nrows = in_sizes[0] / DD;                      // 524288
    const int grid  = nrows / BM;                            // 8192

    hipLaunchKernelGGL(prep_clusters, dim3(KC), dim3(64), 0, stream, clus, wsb);
    hipLaunchKernelGGL(cluster_q_main, dim3(grid), dim3(512), 0, stream,
                       ctx, wsb, out);
}

// Round 17
// 249.216 us; speedup vs baseline: 1.2631x; 1.2631x over previous
//
#include <hip/hip_runtime.h>
#include <hip/hip_bf16.h>

// clusterLayer: q = rownorm( 1 / (1 + ||x||^2 + ||c||^2 - 2 x.cT) )
// N=524288, K=256, D=256. fp32 in/out.
// r17 = r13 structure + simplified aug (the only untested pure diet):
//   - Clusters in ws: -2*bf16(c), 17 frags/nj; aug frag = limbs3(1+|c|^2)
//     at k=256..258. Ctx aug frag is CONSTANT [1,1,1] (k 256..258).
//   - Swapped MFMA: C lane = ctx row, reg = cluster col. After aug step
//     acc = 1 + c2 - 2xc; x2 added as per-lane scalar in pass 1.
//   - vs r13: B2 barrier, wave-0 aug writer, aug LDS rows all REMOVED.
//   - No setprio (r16 post-mortem: negative in barrier-synced blocks).
//   - BM=64, 512 thr = 8 waves; 2 barriers; LDS ~38 KiB;
//     launch_bounds(512,6): ~84 regs, 3 blocks/CU.

#define DD 256
#define KC 256
#define BM 64

typedef __attribute__((ext_vector_type(4)))  float f32x4;
typedef __attribute__((ext_vector_type(16))) float f32x16;
typedef __attribute__((ext_vector_type(8)))  short bf16x8;
typedef __attribute__((ext_vector_type(4)))  short bf16x4;
typedef __attribute__((ext_vector_type(4)))  unsigned u32x4;

__device__ __forceinline__ short f2bf(float f) {
    union { float f; unsigned u; } v; v.f = f;
    unsigned r = (v.u + 0x7fffu + ((v.u >> 16) & 1u)) >> 16;
    return (short)r;
}

__device__ __forceinline__ float bf2f(short h) {
    return __builtin_bit_cast(float, ((unsigned)(unsigned short)h) << 16);
}

__device__ __forceinline__ unsigned cvtpk(float a, float b) {
    unsigned r;
    asm("v_cvt_pk_bf16_f32 %0, %1, %2" : "=v"(r) : "v"(a), "v"(b));
    return r;
}

__device__ __forceinline__ float frcp(float x) {
    return __builtin_amdgcn_rcpf(x);
}

template<int CTRL>
__device__ __forceinline__ float dpp_add(float v) {
    int iv = __builtin_bit_cast(int, v);
    int mv = __builtin_amdgcn_update_dpp(0, iv, CTRL, 0xf, 0xf, false);
    return v + __builtin_bit_cast(float, mv);
}
#define QUAD_SWAP1 0xB1    // quad_perm [1,0,3,2]

__device__ __forceinline__ f32x4 ld4(const float* p) { return *(const f32x4*)p; }

// ---------------- Kernel 0: prep clusters ----------------
// Main frags (nj*17+ks): -2*bf16(c) in 32x32x16 A-operand order.
// Aug frag (nj*17+16), k=256..263 side: [c2h,c2m,c2l,0,...] with
// (c2*) = limbs3(1+|c|^2); k=264..271 side zeros.
__global__ __launch_bounds__(64)
void prep_clusters(const float* __restrict__ clus, short* __restrict__ wsb) {
    const int c = blockIdx.x;      // cluster row 0..255
    const int t = threadIdx.x;     // 0..63, 4 floats each
    f32x4 v = *(const f32x4*)(clus + c * DD + t * 4);
    bf16x4 o;
    o[0] = f2bf(-2.f * v[0]); o[1] = f2bf(-2.f * v[1]);
    o[2] = f2bf(-2.f * v[2]); o[3] = f2bf(-2.f * v[3]);

    const int j    = t >> 1;       // 8-elem chunk index within row (k/8)
    const int ks   = j >> 1;
    const int hi   = j & 1;
    const int half = t & 1;
    const int nj   = c >> 5;
    const int l31  = c & 31;
    *(bf16x4*)&wsb[(((nj * 17 + ks) * 64 + hi * 32 + l31) << 3) + half * 4] = o;

    float s = v[0]*v[0] + v[1]*v[1] + v[2]*v[2] + v[3]*v[3];   // raw |c|^2
    s += __shfl_xor(s, 1);  s += __shfl_xor(s, 2);  s += __shfl_xor(s, 4);
    s += __shfl_xor(s, 8);  s += __shfl_xor(s, 16); s += __shfl_xor(s, 32);
    if (t == 0) {
        float e = 1.f + s;
        short h = f2bf(e);  float e1 = e - bf2f(h);
        short m = f2bf(e1); float e2 = e1 - bf2f(m);
        short l = f2bf(e2);
        u32x4 a;
        a[0] = (unsigned)(unsigned short)h | ((unsigned)(unsigned short)m << 16);
        a[1] = (unsigned)(unsigned short)l;
        a[2] = 0u; a[3] = 0u;
        *(u32x4*)&wsb[((nj * 17 + 16) * 64 + l31) * 8] = a;         // k 256..263
        u32x4 z = {0u, 0u, 0u, 0u};
        *(u32x4*)&wsb[((nj * 17 + 16) * 64 + 32 + l31) * 8] = z;    // k 264..271
    }
}

// ---------------- Main kernel ----------------
__global__ __launch_bounds__(512, 6)
void cluster_q_main(const float* __restrict__ ctx,
                    const short* __restrict__ wsb,
                    float* __restrict__ out) {
    __shared__ short Af[32 * 64 * 8];       // 32 KiB: [j=k/8][row 0..63][8]
    __shared__ float x2p8[8][64];           // per-(wave,row) |x|^2 partials
    __shared__ float rowsum2[8][2][64];     // per-(wave,hi,row) q half-sums

    const int t    = threadIdx.x;
    const int lane = t & 63;
    const int w    = t >> 6;             // wave = col-eighth 0..7
    const int l31  = lane & 31;
    const int hi   = lane >> 5;
    const size_t row0 = (size_t)blockIdx.x * BM;

    // ---- stage A: wave w converts k-slice [w*32, w*32+32) of all 64 rows ----
    {
        const int r0   = lane >> 1;      // row 0..31 (and +32)
        const int half = lane & 1;       // 16-float half of the slice
        f32x4 u[8];
#pragma unroll
        for (int m = 0; m < 2; ++m) {
            const float* src = ctx + (row0 + (size_t)(m * 32 + r0)) * DD
                             + w * 32 + half * 16;
#pragma unroll
            for (int i = 0; i < 4; ++i)
                u[m * 4 + i] = ld4(src + i * 4);
        }
#pragma unroll
        for (int m = 0; m < 2; ++m) {
            float xs = 0.f;
#pragma unroll
            for (int c = 0; c < 2; ++c) {
                f32x4 a0 = u[m * 4 + 2 * c], a1 = u[m * 4 + 2 * c + 1];
                u32x4 o;
                o[0] = cvtpk(a0[0], a0[1]);
                o[1] = cvtpk(a0[2], a0[3]);
                o[2] = cvtpk(a1[0], a1[1]);
                o[3] = cvtpk(a1[2], a1[3]);
                xs += a0[0]*a0[0] + a0[1]*a0[1] + a0[2]*a0[2] + a0[3]*a0[3]
                    + a1[0]*a1[0] + a1[1]*a1[1] + a1[2]*a1[2] + a1[3]*a1[3];
                const int j = w * 4 + half * 2 + c;      // k/8 chunk index
                *(u32x4*)&Af[(j * 64 + m * 32 + r0) * 8] = o;
            }
            xs = dpp_add<QUAD_SWAP1>(xs);                // combine halves
            if (half == 0) x2p8[w][m * 32 + r0] = xs;
        }
    }

    // cluster fragment base: this wave's col-tile nj = w (17 frags)
    const short* bl = wsb + (size_t)(w * 17) * 512 + lane * 8;

    __syncthreads();   // B1: Af + x2p8 ready

    // per-lane |x|^2 totals (lane = ctx row l31 / 32+l31)
    float x2A = 0.f, x2B = 0.f;
#pragma unroll
    for (int q = 0; q < 8; ++q) {
        x2A += x2p8[q][l31];
        x2B += x2p8[q][32 + l31];
    }

    f32x16 acc0 = (f32x16)0.f, acc1 = (f32x16)0.f;

    // clusters: 3-slot rotation, distance 2 (L2 latency cover)
    bf16x8 bs[3];
    bs[0] = *(const bf16x8*)(bl + 0 * 512);
    bs[1] = *(const bf16x8*)(bl + 1 * 512);

    // context frags: ping-pong from LDS
    bf16x8 afA0 = *(const bf16x8*)&Af[((0 + hi) * 64 +  0 + l31) * 8];
    bf16x8 afA1 = *(const bf16x8*)&Af[((0 + hi) * 64 + 32 + l31) * 8];
    bf16x8 afB0, afB1;

#pragma unroll
    for (int ks = 0; ks < 16; ++ks) {
        const int cur = ks % 3;
        const bool even = (ks & 1) == 0;

        if (ks < 14)
            bs[(ks + 2) % 3] = *(const bf16x8*)(bl + (ks + 2) * 512);
        if (ks < 15) {
            const int jn = (ks + 1) * 2 + hi;
            bf16x8 v0 = *(const bf16x8*)&Af[(jn * 64 +  0 + l31) * 8];
            bf16x8 v1 = *(const bf16x8*)&Af[(jn * 64 + 32 + l31) * 8];
            if (even) { afB0 = v0; afB1 = v1; }
            else      { afA0 = v0; afA1 = v1; }
        }

        const bf16x8 a0 = even ? afA0 : afB0;
        const bf16x8 a1 = even ? afA1 : afB1;
        acc0 = __builtin_amdgcn_mfma_f32_32x32x16_bf16(bs[cur], a0, acc0, 0, 0, 0);
        acc1 = __builtin_amdgcn_mfma_f32_32x32x16_bf16(bs[cur], a1, acc1, 0, 0, 0);
    }

    // ---- aug step: acc += (1+|c|^2) per cluster -> acc = 1 + c2 - 2xc ----
    {
        bf16x8 bsa = *(const bf16x8*)(bl + 16 * 512);
        bf16x8 ctx_aug = (bf16x8)0;
        if (hi == 0) {
            ctx_aug[0] = (short)0x3F80; ctx_aug[1] = (short)0x3F80;
            ctx_aug[2] = (short)0x3F80;
        }
        acc0 = __builtin_amdgcn_mfma_f32_32x32x16_bf16(bsa, ctx_aug, acc0, 0, 0, 0);
        acc1 = __builtin_amdgcn_mfma_f32_32x32x16_bf16(bsa, ctx_aug, acc1, 0, 0, 0);
    }

    // ---- pass 1: q = rcp(acc + x2lane), in-lane half-row sums ----
    float s0 = 0.f, s1 = 0.f;
#pragma unroll
    for (int r = 0; r < 16; ++r) {
        acc0[r] = frcp(acc0[r] + x2A); s0 += acc0[r];
        acc1[r] = frcp(acc1[r] + x2B); s1 += acc1[r];
    }
    rowsum2[w][hi][l31]      = s0;
    rowsum2[w][hi][32 + l31] = s1;
    __syncthreads();   // B2

    // ---- pass 2: row totals, normalize, dwordx4 stores ----
    float t0 = 0.f, t1 = 0.f;
#pragma unroll
    for (int q = 0; q < 8; ++q) {
        t0 += rowsum2[q][0][l31]      + rowsum2[q][1][l31];
        t1 += rowsum2[q][0][32 + l31] + rowsum2[q][1][32 + l31];
    }
    const float inv0 = frcp(t0);
    const float inv1 = frcp(t1);

    float* op0 = out + (row0 + (size_t)l31) * KC        + w * 32 + 4 * hi;
    float* op1 = out + (row0 + (size_t)(32 + l31)) * KC + w * 32 + 4 * hi;
#pragma unroll
    for (int i = 0; i < 4; ++i) {
        f32x4 v0, v1;
#pragma unroll
        for (int j = 0; j < 4; ++j) {
            v0[j] = acc0[4 * i + j] * inv0;   // cluster col = 8i + 4hi + j
            v1[j] = acc1[4 * i + j] * inv1;
        }
        *(f32x4*)(op0 + 8 * i) = v0;
        *(f32x4*)(op1 + 8 * i) = v1;
    }
}

extern "C" void kernel_launch(void* const* d_in, const int* in_sizes, int n_in,
                              void* d_out, int out_size, void* d_ws, size_t ws_size,
                              hipStream_t stream) {
    const float* ctx  = (const float*)d_in[0];
    const float* clus = (const float*)d_in[1];
    float* out = (float*)d_out;

    short* wsb = (short*)d_ws;     // cluster fragment image (8*17 KiB = 136 KiB)

    const int nrows = in_sizes[0] / DD;                      // 524288
    const int grid  = nrows / BM;                            // 8192

    hipLaunchKernelGGL(prep_clusters, dim3(KC), dim3(64), 0, stream, clus, wsb);
    hipLaunchKernelGGL(cluster_q_main, dim3(grid), dim3(512), 0, stream,
                       ctx, wsb, out);
}

// Round 18
// 237.868 us; speedup vs baseline: 1.3234x; 1.0477x over previous
//
#include <hip/hip_runtime.h>
#include <hip/hip_bf16.h>

// clusterLayer: q = rownorm( 1 / (1 + ||x||^2 + ||c||^2 - 2 x.cT) )
// N=524288, K=256, D=256. fp32 in/out.
// r18 = r13 verbatim (best measured: 244.0 us) — session-final pin +
// reproducibility check on the r13-vs-r17 2% delta.
//   - Clusters in ws: -2*bf16(c), 17 frags/nj; frag16 = aug
//     [1,1,1, limbs3(1+|c|^2)] per cluster lane (k=256..263 side).
//   - Context staged to LDS (frag order) + aug rows [limbs3(|x|^2),1,1,1]
//     written by wave 0 from x2 partials.
//   - mfma(cluster_frag, context_frag): C lane = context row, reg = cluster.
//     After 17 K-steps acc = 1 + d. q = rcp(acc): no d-math, no c2/x2
//     plumbing, no DPP tree (row sum is IN-LANE), stores are dwordx4
//     directly from acc (4-reg groups = 4 consecutive output columns).
//   - BM=64, 512 thr = 8 waves = 8 col-eighths x 2 M-tiles; 3 barriers.

#define DD 256
#define KC 256
#define BM 64

typedef __attribute__((ext_vector_type(4)))  float f32x4;
typedef __attribute__((ext_vector_type(16))) float f32x16;
typedef __attribute__((ext_vector_type(8)))  short bf16x8;
typedef __attribute__((ext_vector_type(4)))  short bf16x4;
typedef __attribute__((ext_vector_type(4)))  unsigned u32x4;

__device__ __forceinline__ short f2bf(float f) {
    union { float f; unsigned u; } v; v.f = f;
    unsigned r = (v.u + 0x7fffu + ((v.u >> 16) & 1u)) >> 16;
    return (short)r;
}

__device__ __forceinline__ float bf2f(short h) {
    return __builtin_bit_cast(float, ((unsigned)(unsigned short)h) << 16);
}

// packed fp32->bf16 RNE: dst.lo = cvt(a), dst.hi = cvt(b)
__device__ __forceinline__ unsigned cvtpk(float a, float b) {
    unsigned r;
    asm("v_cvt_pk_bf16_f32 %0, %1, %2" : "=v"(r) : "v"(a), "v"(b));
    return r;
}

__device__ __forceinline__ float frcp(float x) {
    return __builtin_amdgcn_rcpf(x);
}

// v += dpp_move(v, CTRL); VALU pipe.
template<int CTRL>
__device__ __forceinline__ float dpp_add(float v) {
    int iv = __builtin_bit_cast(int, v);
    int mv = __builtin_amdgcn_update_dpp(0, iv, CTRL, 0xf, 0xf, false);
    return v + __builtin_bit_cast(float, mv);
}
#define QUAD_SWAP1 0xB1    // quad_perm [1,0,3,2]

__device__ __forceinline__ f32x4 ld4(const float* p) { return *(const f32x4*)p; }

// ---------------- Kernel 0: prep clusters ----------------
// Stores -2*bf16(c) main frags (idx nj*17+ks) + aug frag (nj*17+16):
// hi=0 lane slots = [1,1,1, c2h,c2m,c2l, 0,0] with (c2*) = limbs3(1+|c|^2).
__global__ __launch_bounds__(64)
void prep_clusters(const float* __restrict__ clus, short* __restrict__ wsb) {
    const int c = blockIdx.x;      // cluster row 0..255
    const int t = threadIdx.x;     // 0..63, 4 floats each
    f32x4 v = *(const f32x4*)(clus + c * DD + t * 4);
    bf16x4 o;
    o[0] = f2bf(-2.f * v[0]); o[1] = f2bf(-2.f * v[1]);
    o[2] = f2bf(-2.f * v[2]); o[3] = f2bf(-2.f * v[3]);

    const int j    = t >> 1;       // 8-elem chunk index within row (k/8)
    const int ks   = j >> 1;
    const int hi   = j & 1;
    const int half = t & 1;
    const int nj   = c >> 5;
    const int l31  = c & 31;
    *(bf16x4*)&wsb[(((nj * 17 + ks) * 64 + hi * 32 + l31) << 3) + half * 4] = o;

    float s = v[0]*v[0] + v[1]*v[1] + v[2]*v[2] + v[3]*v[3];   // raw |c|^2
    s += __shfl_xor(s, 1);  s += __shfl_xor(s, 2);  s += __shfl_xor(s, 4);
    s += __shfl_xor(s, 8);  s += __shfl_xor(s, 16); s += __shfl_xor(s, 32);
    if (t == 0) {
        float e = 1.f + s;
        short h = f2bf(e);  float e1 = e - bf2f(h);
        short m = f2bf(e1); float e2 = e1 - bf2f(m);
        short l = f2bf(e2);
        const unsigned one = 0x3F80u;
        u32x4 a;
        a[0] = one | (one << 16);
        a[1] = one | ((unsigned)(unsigned short)h << 16);
        a[2] = (unsigned)(unsigned short)m | ((unsigned)(unsigned short)l << 16);
        a[3] = 0u;
        *(u32x4*)&wsb[((nj * 17 + 16) * 64 + l31) * 8] = a;         // hi=0 slots
        u32x4 z = {0u, 0u, 0u, 0u};
        *(u32x4*)&wsb[((nj * 17 + 16) * 64 + 32 + l31) * 8] = z;    // hi=1 slots
    }
}

// ---------------- Main kernel ----------------
__global__ __launch_bounds__(512, 6)
void cluster_q_main(const float* __restrict__ ctx,
                    const short* __restrict__ wsb,
                    float* __restrict__ out) {
    __shared__ short Af[34 * 64 * 8];    // 34 KiB: j=0..31 main, 32..33 aug
    __shared__ float x2p8[8][64];        // per-(wave,row) |x|^2 partials
    __shared__ float rowsum2[8][2][64];  // per-(wave,hi,row) q half-sums

    const int t    = threadIdx.x;
    const int lane = t & 63;
    const int w    = t >> 6;             // wave = col-eighth 0..7
    const int l31  = lane & 31;
    const int hi   = lane >> 5;
    const size_t row0 = (size_t)blockIdx.x * BM;

    // ---- stage A: wave w converts k-slice [w*32, w*32+32) of all 64 rows ----
    {
        const int r0   = lane >> 1;      // row 0..31 (and +32)
        const int half = lane & 1;       // 16-float half of the slice
        f32x4 u[8];
#pragma unroll
        for (int m = 0; m < 2; ++m) {
            const float* src = ctx + (row0 + (size_t)(m * 32 + r0)) * DD
                             + w * 32 + half * 16;
#pragma unroll
            for (int i = 0; i < 4; ++i)
                u[m * 4 + i] = ld4(src + i * 4);
        }
#pragma unroll
        for (int m = 0; m < 2; ++m) {
            float xs = 0.f;
#pragma unroll
            for (int c = 0; c < 2; ++c) {
                f32x4 a0 = u[m * 4 + 2 * c], a1 = u[m * 4 + 2 * c + 1];
                u32x4 o;
                o[0] = cvtpk(a0[0], a0[1]);
                o[1] = cvtpk(a0[2], a0[3]);
                o[2] = cvtpk(a1[0], a1[1]);
                o[3] = cvtpk(a1[2], a1[3]);
                xs += a0[0]*a0[0] + a0[1]*a0[1] + a0[2]*a0[2] + a0[3]*a0[3]
                    + a1[0]*a1[0] + a1[1]*a1[1] + a1[2]*a1[2] + a1[3]*a1[3];
                const int j = w * 4 + half * 2 + c;      // k/8 chunk index
                *(u32x4*)&Af[(j * 64 + m * 32 + r0) * 8] = o;
            }
            xs = dpp_add<QUAD_SWAP1>(xs);                // combine halves
            if (half == 0) x2p8[w][m * 32 + r0] = xs;
        }
    }

    // cluster fragment base: this wave's col-tile nj = w (17 frags)
    const short* bl = wsb + (size_t)(w * 17) * 512 + lane * 8;

    __syncthreads();   // B1: Af main + x2p8 ready

    // ---- wave 0 writes the context aug rows: [x2h,x2m,x2l,1,1,1,0,0] ----
    if (w == 0) {
        float e = 0.f;
#pragma unroll
        for (int q = 0; q < 8; ++q) e += x2p8[q][lane];
        short h = f2bf(e);  float e1 = e - bf2f(h);
        short m = f2bf(e1); float e2 = e1 - bf2f(m);
        short l = f2bf(e2);
        const unsigned one = 0x3F80u;
        u32x4 o;
        o[0] = (unsigned)(unsigned short)h | ((unsigned)(unsigned short)m << 16);
        o[1] = (unsigned)(unsigned short)l | (one << 16);
        o[2] = one | (one << 16);
        o[3] = 0u;
        *(u32x4*)&Af[(32 * 64 + lane) * 8] = o;          // hi=0 slots
        u32x4 z = {0u, 0u, 0u, 0u};
        *(u32x4*)&Af[(33 * 64 + lane) * 8] = z;          // hi=1 slots
    }

    f32x16 acc0 = (f32x16)0.f, acc1 = (f32x16)0.f;

    // clusters: 3-slot rotation, distance 2 (L2 latency cover)
    bf16x8 bs[3];
    bs[0] = *(const bf16x8*)(bl + 0 * 512);
    bs[1] = *(const bf16x8*)(bl + 1 * 512);

    // context frags: ping-pong from LDS
    bf16x8 afA0 = *(const bf16x8*)&Af[((0 + hi) * 64 +  0 + l31) * 8];
    bf16x8 afA1 = *(const bf16x8*)&Af[((0 + hi) * 64 + 32 + l31) * 8];
    bf16x8 afB0, afB1;

#pragma unroll
    for (int ks = 0; ks < 16; ++ks) {
        const int cur = ks % 3;
        const bool even = (ks & 1) == 0;

        if (ks < 14)
            bs[(ks + 2) % 3] = *(const bf16x8*)(bl + (ks + 2) * 512);
        if (ks < 15) {
            const int jn = (ks + 1) * 2 + hi;
            bf16x8 v0 = *(const bf16x8*)&Af[(jn * 64 +  0 + l31) * 8];
            bf16x8 v1 = *(const bf16x8*)&Af[(jn * 64 + 32 + l31) * 8];
            if (even) { afB0 = v0; afB1 = v1; }
            else      { afA0 = v0; afA1 = v1; }
        }

        const bf16x8 a0 = even ? afA0 : afB0;
        const bf16x8 a1 = even ? afA1 : afB1;
        // SWAPPED: C col(lane) = context row, C row(reg) = cluster
        acc0 = __builtin_amdgcn_mfma_f32_32x32x16_bf16(bs[cur], a0, acc0, 0, 0, 0);
        acc1 = __builtin_amdgcn_mfma_f32_32x32x16_bf16(bs[cur], a1, acc1, 0, 0, 0);
    }

    // aug cluster frag (prefetch before barrier)
    bf16x8 bsa = *(const bf16x8*)(bl + 16 * 512);

    __syncthreads();   // B2: context aug rows visible

    {
        bf16x8 aa0 = *(const bf16x8*)&Af[((32 + hi) * 64 +  0 + l31) * 8];
        bf16x8 aa1 = *(const bf16x8*)&Af[((32 + hi) * 64 + 32 + l31) * 8];
        acc0 = __builtin_amdgcn_mfma_f32_32x32x16_bf16(bsa, aa0, acc0, 0, 0, 0);
        acc1 = __builtin_amdgcn_mfma_f32_32x32x16_bf16(bsa, aa1, acc1, 0, 0, 0);
        // acc = 1 + d
    }

    // ---- pass 1: q = rcp(acc), IN-LANE half-row sums ----
    float s0 = 0.f, s1 = 0.f;
#pragma unroll
    for (int r = 0; r < 16; ++r) {
        acc0[r] = frcp(acc0[r]); s0 += acc0[r];
        acc1[r] = frcp(acc1[r]); s1 += acc1[r];
    }
    rowsum2[w][hi][l31]      = s0;   // row l31, this hi's 16 clusters
    rowsum2[w][hi][32 + l31] = s1;   // row 32+l31
    __syncthreads();   // B3

    // ---- pass 2: row totals, normalize, dwordx4 stores from acc ----
    float t0 = 0.f, t1 = 0.f;
#pragma unroll
    for (int q = 0; q < 8; ++q) {
        t0 += rowsum2[q][0][l31]      + rowsum2[q][1][l31];
        t1 += rowsum2[q][0][32 + l31] + rowsum2[q][1][32 + l31];
    }
    const float inv0 = frcp(t0);
    const float inv1 = frcp(t1);

    float* op0 = out + (row0 + (size_t)l31) * KC        + w * 32 + 4 * hi;
    float* op1 = out + (row0 + (size_t)(32 + l31)) * KC + w * 32 + 4 * hi;
#pragma unroll
    for (int i = 0; i < 4; ++i) {
        f32x4 v0, v1;
#pragma unroll
        for (int j = 0; j < 4; ++j) {
            v0[j] = acc0[4 * i + j] * inv0;   // cluster col = 8i + 4hi + j
            v1[j] = acc1[4 * i + j] * inv1;
        }
        *(f32x4*)(op0 + 8 * i) = v0;
        *(f32x4*)(op1 + 8 * i) = v1;
    }
}

extern "C" void kernel_launch(void* const* d_in, const int* in_sizes, int n_in,
                              void* d_out, int out_size, void* d_ws, size_t ws_size,
                              hipStream_t stream) {
    const float* ctx  = (const float*)d_in[0];
    const float* clus = (const float*)d_in[1];
    float* out = (float*)d_out;

    short* wsb = (short*)d_ws;     // cluster fragment image (8*17 KiB = 136 KiB)

    const int nrows = in_sizes[0] / DD;                      // 524288
    const int grid  = nrows / BM;                            // 8192

    hipLaunchKernelGGL(prep_clusters, dim3(KC), dim3(64), 0, stream, clus, wsb);
    hipLaunchKernelGGL(cluster_q_main, dim3(grid), dim3(512), 0, stream,
                       ctx, wsb, out);
}